// Round 1
// baseline (1229.860 us; speedup 1.0000x reference)
//
#include <hip/hip_runtime.h>
#include <math.h>

#define TE 16
#define NTHREADS 256
#define HID 256
#define WNUM 1024

// Fully fused NequIP edge kernel.
// Per block: 16 edges. Stages: gather inputs -> h=silu(emb@W1+b1) in LDS ->
// w = h@W2+b2 in registers (thread t owns cols {t, t+256, t+512, t+768}) ->
// per-type LDS writeback + contraction to 64 edge features -> atomic scatter.
__global__ __launch_bounds__(NTHREADS, 2)
void nequip_fused(const float* __restrict__ node_features,
                  const float* __restrict__ edge_attr,
                  const float* __restrict__ edge_emb,
                  const float* __restrict__ W1,
                  const float* __restrict__ b1,
                  const float* __restrict__ W2,
                  const float* __restrict__ b2,
                  const int* __restrict__ edge_src,
                  const int* __restrict__ edge_dst,
                  float* __restrict__ out,
                  int E)
{
    __shared__ float sH[TE][HID];     // 16 KB  h tile
    __shared__ float sWt[TE][256];    // 16 KB  one w-type slab at a time
    __shared__ float sX[TE][64];      // 4 KB   gathered node features
    __shared__ float sEmb[TE][18];
    __shared__ float sAttr[TE][4];
    __shared__ int   sSrc[TE];
    __shared__ int   sDst[TE];

    const int t  = threadIdx.x;
    const int e0 = blockIdx.x * TE;

    // ---- stage small per-edge inputs ----
    if (t < TE) {
        const int ee = e0 + t;
        sSrc[t] = (ee < E) ? edge_src[ee] : 0;
        sDst[t] = (ee < E) ? edge_dst[ee] : 0;
    }
    if (t < TE * 4) {
        const int e = t >> 2, c = t & 3;
        const int ee = e0 + e;
        sAttr[e][c] = (ee < E) ? edge_attr[(size_t)ee * 4 + c] : 0.f;
    }
    for (int idx = t; idx < TE * 18; idx += NTHREADS) {
        const int e = idx / 18, k = idx - e * 18;
        const int ee = e0 + e;
        sEmb[e][k] = (ee < E) ? edge_emb[(size_t)ee * 18 + k] : 0.f;
    }
    __syncthreads();

    // ---- gather node features for edge sources ----
    for (int idx = t; idx < TE * 64; idx += NTHREADS) {
        const int e = idx >> 6, c = idx & 63;
        sX[e][c] = node_features[(size_t)sSrc[e] * 64 + c];
    }

    // ---- h = silu(emb @ W1 + b1): iteration m = edge m, column j = t ----
    for (int m = 0; m < TE; ++m) {
        float acc = b1[t];
        #pragma unroll
        for (int k = 0; k < 18; ++k)
            acc = fmaf(sEmb[m][k], W1[k * HID + t], acc);
        sH[m][t] = acc * (1.f / (1.f + __expf(-acc)));   // silu
    }
    __syncthreads();

    // ---- w = h @ W2 + b2 ; thread t owns n = r*256+t, r=0..3, all 16 edges ----
    float acc[TE][4];
    {
        float bv[4];
        #pragma unroll
        for (int r = 0; r < 4; ++r) bv[r] = b2[r * 256 + t];
        #pragma unroll
        for (int e = 0; e < TE; ++e)
            #pragma unroll
            for (int r = 0; r < 4; ++r) acc[e][r] = bv[r];
    }
    for (int k = 0; k < HID; k += 4) {
        float w2v[4][4];
        #pragma unroll
        for (int kk = 0; kk < 4; ++kk)
            #pragma unroll
            for (int r = 0; r < 4; ++r)
                w2v[kk][r] = W2[(size_t)(k + kk) * WNUM + r * 256 + t];
        #pragma unroll
        for (int e = 0; e < TE; ++e) {
            const float4 hv = *(const float4*)(&sH[e][k]);
            #pragma unroll
            for (int r = 0; r < 4; ++r)
                acc[e][r] = fmaf(hv.x, w2v[0][r],
                            fmaf(hv.y, w2v[1][r],
                            fmaf(hv.z, w2v[2][r],
                            fmaf(hv.w, w2v[3][r], acc[e][r]))));
        }
    }

    // ---- contraction: thread t -> (edge ce, output col cj) ----
    const int ce = t >> 4;
    const int cj = t & 15;
    const float y0  = sAttr[ce][0];
    const float y1x = sAttr[ce][1], y1y = sAttr[ce][2], y1z = sAttr[ce][3];

    float r_ss = 0.f, r_vv = 0.f, r_sv = 0.f;
    float r_vs0 = 0.f, r_vs1 = 0.f, r_vs2 = 0.f;

    #pragma unroll
    for (int r = 0; r < 4; ++r) {
        __syncthreads();   // previous slab's reads done
        #pragma unroll
        for (int e = 0; e < TE; ++e) sWt[e][t] = acc[e][r];
        __syncthreads();   // slab visible
        if (r == 0) {
            #pragma unroll
            for (int i = 0; i < 16; ++i)
                r_ss = fmaf(sWt[ce][i * 16 + cj], sX[ce][i], r_ss);
        } else if (r == 1) {
            #pragma unroll
            for (int i = 0; i < 16; ++i) {
                const float di = y1x * sX[ce][16 + i * 3]
                               + y1y * sX[ce][16 + i * 3 + 1]
                               + y1z * sX[ce][16 + i * 3 + 2];
                r_vv = fmaf(sWt[ce][i * 16 + cj], di, r_vv);
            }
        } else if (r == 2) {
            #pragma unroll
            for (int i = 0; i < 16; ++i)
                r_sv = fmaf(sWt[ce][i * 16 + cj], sX[ce][i], r_sv);
        } else {
            #pragma unroll
            for (int i = 0; i < 16; ++i) {
                const float w3 = sWt[ce][i * 16 + cj];
                r_vs0 = fmaf(w3, sX[ce][16 + i * 3],     r_vs0);
                r_vs1 = fmaf(w3, sX[ce][16 + i * 3 + 1], r_vs1);
                r_vs2 = fmaf(w3, sX[ce][16 + i * 3 + 2], r_vs2);
            }
        }
    }

    // c_s = sqrt(1/32); c_v*inv_sqrt3 = sqrt(3/32)/sqrt(3) = c_s.
    // Fold the final /sqrt(E/N)=/4:  CC = sqrt(1/32)/4
    const float CC   = 0.04419417382415922f;
    const float INV3 = 0.5773502691896258f;

    const float o_s = CC * fmaf(y0, r_ss, INV3 * r_vv);
    const float ov0 = CC * (r_sv * y1x + y0 * r_vs0);
    const float ov1 = CC * (r_sv * y1y + y0 * r_vs1);
    const float ov2 = CC * (r_sv * y1z + y0 * r_vs2);

    if (e0 + ce < E) {
        float* op = out + (size_t)sDst[ce] * 64;
        atomicAdd(op + cj, o_s);
        atomicAdd(op + 16 + cj * 3 + 0, ov0);
        atomicAdd(op + 16 + cj * 3 + 1, ov1);
        atomicAdd(op + 16 + cj * 3 + 2, ov2);
    }
}

extern "C" void kernel_launch(void* const* d_in, const int* in_sizes, int n_in,
                              void* d_out, int out_size, void* d_ws, size_t ws_size,
                              hipStream_t stream)
{
    const float* node_features = (const float*)d_in[0];
    const float* edge_attr     = (const float*)d_in[1];
    const float* edge_emb      = (const float*)d_in[2];
    const float* W1            = (const float*)d_in[3];
    const float* b1            = (const float*)d_in[4];
    const float* W2            = (const float*)d_in[5];
    const float* b2            = (const float*)d_in[6];
    const int*   edge_src      = (const int*)d_in[7];
    const int*   edge_dst      = (const int*)d_in[8];
    float*       out           = (float*)d_out;

    const int E = in_sizes[7];          // edge_src element count

    // d_out is poisoned before every launch; atomics need zeros.
    hipMemsetAsync(out, 0, (size_t)out_size * sizeof(float), stream);

    const int blocks = (E + TE - 1) / TE;
    nequip_fused<<<blocks, NTHREADS, 0, stream>>>(
        node_features, edge_attr, edge_emb, W1, b1, W2, b2,
        edge_src, edge_dst, out, E);
}

// Round 2
// 1224.895 us; speedup vs baseline: 1.0041x; 1.0041x over previous
//
#include <hip/hip_runtime.h>
#include <math.h>

// ---------------------------------------------------------------------------
// NequIP fused edge kernel, round 1: MFMA (bf16 32x32x16) for the h@W2 GEMM.
//
// Structure per 64-edge block (256 thr = 4 waves, 2 blocks/CU):
//  phase1: stage emb/attr/dst, gather node features, build fp32 contraction
//          coefficient tables (transposed [i][e] for float4 quad reads),
//          zero LDS result accumulators.  (CC, 1/sqrt3 folded into coefs.)
//  phase2: h = silu(emb@W1+b1) in fp32 VALU -> packed bf16 into LDS in
//          MFMA A-frag order with XOR swizzle (conflict-free write & read).
//          First B-fragments prefetched from L2 during this phase.
//  phase3: barrier-free K-loop: per 256-col type slab, 16 kiters of
//          v_mfma_f32_32x32x16_bf16; B-frags direct global->VGPR (W2
//          pre-converted to bf16 [n][k] in d_ws, L2-resident), register
//          double-buffered 2 kiters ahead. Epilogue contracts the slab from
//          accumulator registers into LDS resS/resV via ds_add_f32.
//  phase4: scatter-add 64 features/edge to out with fp32 global atomics.
// ---------------------------------------------------------------------------

typedef __attribute__((ext_vector_type(8))) short s8v;    // 8 x bf16 (4 VGPR)
typedef __attribute__((ext_vector_type(16))) float f16v;  // 32x32 acc (16 f32)
typedef unsigned short ushort_t;
typedef unsigned int uint_t;

#define NTHR 256
#define TE 64

__device__ __forceinline__ ushort_t f2bf(float x) {
    uint_t u = __float_as_uint(x);
    u += 0x7fffu + ((u >> 16) & 1u);   // round-to-nearest-even
    return (ushort_t)(u >> 16);
}

// W2 [256][1024] fp32 -> W2bf [1024][256] bf16 (transposed, k-contiguous).
__global__ void conv_w2(const float* __restrict__ W2, ushort_t* __restrict__ W2bf) {
    int idx = blockIdx.x * 256 + threadIdx.x;      // 65536 threads, 4 k each
    int n  = idx & 1023;
    int k4 = (idx >> 10) << 2;
    uint_t lo = (uint_t)f2bf(W2[(size_t)(k4 + 0) * 1024 + n]) |
                ((uint_t)f2bf(W2[(size_t)(k4 + 1) * 1024 + n]) << 16);
    uint_t hi = (uint_t)f2bf(W2[(size_t)(k4 + 2) * 1024 + n]) |
                ((uint_t)f2bf(W2[(size_t)(k4 + 3) * 1024 + n]) << 16);
    ((uint2*)W2bf)[(n * 256 + k4) >> 2] = make_uint2(lo, hi);
}

__global__ __launch_bounds__(NTHR, 2)
void nequip_mfma(const float* __restrict__ nodef,
                 const float* __restrict__ eattr,
                 const float* __restrict__ eemb,
                 const float* __restrict__ W1,
                 const float* __restrict__ b1,
                 const ushort_t* __restrict__ W2bf,
                 const float* __restrict__ b2,
                 const int* __restrict__ esrc,
                 const int* __restrict__ edst,
                 float* __restrict__ out,
                 int E, float CC)
{
    __shared__ __align__(16) ushort_t sAu[TE * 256];   // 32 KB h bf16, frag order
    __shared__ __align__(16) float sEmb[TE * 18];      // 4.5 KB
    __shared__ __align__(16) float sCss[16 * 64];      // coef[i][e] = CC*y0*s
    __shared__ __align__(16) float sCvv[16 * 64];      // CC/sqrt3*(y1.v)
    __shared__ __align__(16) float sCsv[16 * 64];      // CC*s
    __shared__ __align__(16) float sCvs[48 * 64];      // [(i*3+a)][e] = CC*y0*v
    __shared__ __align__(16) float sAttrT[4 * 64];     // [c][e] y0,y1x,y1y,y1z
    __shared__ __align__(16) float resS[64 * 16];      // out_s accum
    __shared__ __align__(16) float resV[64 * 48];      // out_v accum
    __shared__ int sDst[TE];

    const int t  = threadIdx.x;
    const int e0 = blockIdx.x * TE;

    // ---------------- phase 1: staging + coefs + res zero ----------------
    for (int idx = t; idx < TE * 18; idx += NTHR) {
        size_t g = (size_t)e0 * 18 + idx;
        sEmb[idx] = (g < (size_t)E * 18) ? eemb[g] : 0.f;
    }
    if (t < TE) {
        int ge = e0 + t;
        float4 a = make_float4(0.f, 0.f, 0.f, 0.f);
        int d = 0;
        if (ge < E) { a = *(const float4*)(eattr + (size_t)ge * 4); d = edst[ge]; }
        sAttrT[0 * 64 + t] = a.x; sAttrT[1 * 64 + t] = a.y;
        sAttrT[2 * 64 + t] = a.z; sAttrT[3 * 64 + t] = a.w;
        sDst[t] = d;
    }
    for (int idx = t; idx < 64 * 16; idx += NTHR) resS[idx] = 0.f;
    for (int idx = t; idx < 64 * 48; idx += NTHR) resV[idx] = 0.f;

    {   // coef tables: thread t -> edge e = t>>2, i-quad iq = t&3
        const int e = t >> 2, iq = t & 3;
        const int ge = e0 + e;
        const bool ok = ge < E;
        float y0 = 0.f, y1x = 0.f, y1y = 0.f, y1z = 0.f;
        int src = 0;
        if (ok) {
            float4 a = *(const float4*)(eattr + (size_t)ge * 4);
            y0 = a.x; y1x = a.y; y1y = a.z; y1z = a.w;
            src = esrc[ge];
        }
        const float* xp = nodef + (size_t)src * 64;
        float4 z = make_float4(0.f, 0.f, 0.f, 0.f);
        float4 sv = ok ? *(const float4*)(xp + iq * 4) : z;
        float4 v0 = ok ? *(const float4*)(xp + 16 + iq * 12) : z;
        float4 v1 = ok ? *(const float4*)(xp + 16 + iq * 12 + 4) : z;
        float4 v2 = ok ? *(const float4*)(xp + 16 + iq * 12 + 8) : z;
        const float K3 = CC * 0.57735026918962576f;   // CC/sqrt(3)
        float sarr[4] = { sv.x, sv.y, sv.z, sv.w };
        float varr[12] = { v0.x, v0.y, v0.z, v0.w, v1.x, v1.y, v1.z, v1.w,
                           v2.x, v2.y, v2.z, v2.w };
        #pragma unroll
        for (int j = 0; j < 4; ++j) {
            const int i = iq * 4 + j;
            const float s  = sarr[j];
            const float vx = varr[j * 3 + 0], vy = varr[j * 3 + 1], vz = varr[j * 3 + 2];
            sCss[i * 64 + e] = CC * y0 * s;
            sCvv[i * 64 + e] = K3 * (y1x * vx + y1y * vy + y1z * vz);
            sCsv[i * 64 + e] = CC * s;
            sCvs[(i * 3 + 0) * 64 + e] = CC * y0 * vx;
            sCvs[(i * 3 + 1) * 64 + e] = CC * y0 * vy;
            sCvs[(i * 3 + 2) * 64 + e] = CC * y0 * vz;
        }
    }
    __syncthreads();

    // ---------------- B-frag addressing + initial prefetch ----------------
    const int lane = t & 63;
    const int w    = t >> 6;          // wave id 0..3
    const int l31  = lane & 31;
    const int eh5  = lane >> 5;
    // W2bf [n][k]: frag element (n = slab*256 + nt*32 + l31, k = ki*16 + eh5*8)
    const ushort_t* Bbase0 = W2bf + ((size_t)(w * 32 + l31) * 256 + eh5 * 8);
    const ushort_t* Bbase1 = W2bf + ((size_t)((w + 4) * 32 + l31) * 256 + eh5 * 8);
    // + r*65536 + kk*32 + f*16 (ushort units)

    s8v bc00 = *(const s8v*)(Bbase0);
    s8v bc01 = *(const s8v*)(Bbase0 + 16);
    s8v bc10 = *(const s8v*)(Bbase1);
    s8v bc11 = *(const s8v*)(Bbase1 + 16);

    // ---------------- phase 2: h = silu(emb@W1+b1) -> sA (bf16 frag order) --
    {
        const int p = t & 127;         // column pair p -> cols 2p, 2p+1
        const int ehalf = t >> 7;      // edge half (e = ehalf*32 + er)
        const int n0 = 2 * p;
        float w1a[18], w1b[18];
        #pragma unroll
        for (int m = 0; m < 18; ++m) {
            float2 wv = *(const float2*)(W1 + m * 256 + n0);
            w1a[m] = wv.x; w1b[m] = wv.y;
        }
        const float2 bv = *(const float2*)(b1 + n0);
        const int ki = p >> 3;                      // k-iter of this col pair
        const int wordBase = (ehalf * 16 + ki) * 64;
        const int wsub = p & 3;                     // word within 16B frag
        uint_t* sA32 = (uint_t*)sAu;
        for (int er = 0; er < 32; ++er) {
            const int e = ehalf * 32 + er;
            float a0 = bv.x, a1 = bv.y;
            const float* ep = sEmb + e * 18;
            #pragma unroll
            for (int m = 0; m < 18; ++m) {
                const float em = ep[m];
                a0 = fmaf(em, w1a[m], a0);
                a1 = fmaf(em, w1b[m], a1);
            }
            a0 = a0 / (1.f + __expf(-a0));          // silu
            a1 = a1 / (1.f + __expf(-a1));
            const uint_t pk = (uint_t)f2bf(a0) | ((uint_t)f2bf(a1) << 16);
            const int lane_s  = (e & 31) + 32 * ((p >> 2) & 1);
            const int lane_sw = lane_s ^ (ki & 7);  // XOR swizzle (bank spread)
            sA32[(wordBase + lane_sw) * 4 + wsub] = pk;
        }
    }
    __syncthreads();

    // ---------------- phase 3: MFMA K-loop + per-slab contraction ----------
    const int ip = (lane >> 4) & 1;   // i parity within an N-tile
    const int jj = lane & 15;         // output column j
    const int i0 = 2 * w + ip;        // i of tile nt=w
    const int i1 = 2 * w + 8 + ip;    // i of tile nt=w+4

    #pragma unroll 1
    for (int r = 0; r < 4; ++r) {     // slab = weight type (ss, vv, sv, vs)
        const float bz0 = b2[r * 256 + w * 32 + l31];
        const float bz1 = b2[r * 256 + (w + 4) * 32 + l31];
        f16v a00, a01, a10, a11;      // [mtile][ntile]
        #pragma unroll
        for (int q = 0; q < 16; ++q) { a00[q] = bz0; a01[q] = bz1; a10[q] = bz0; a11[q] = bz1; }

        #pragma unroll
        for (int kk = 0; kk < 8; ++kk) {          // kiter pairs
            // prefetch B for next kiter pair (possibly next slab)
            const int s2 = r * 8 + kk;
            const int s3 = (s2 + 1 < 32) ? (s2 + 1) : s2;   // clamp, harmless reload
            const int rn = s3 >> 3, kn = s3 & 7;
            const ushort_t* p0 = Bbase0 + (size_t)rn * 65536 + kn * 32;
            const ushort_t* p1 = Bbase1 + (size_t)rn * 65536 + kn * 32;
            s8v bn00 = *(const s8v*)(p0);
            s8v bn01 = *(const s8v*)(p0 + 16);
            s8v bn10 = *(const s8v*)(p1);
            s8v bn11 = *(const s8v*)(p1 + 16);

            #pragma unroll
            for (int f = 0; f < 2; ++f) {
                const int ki = kk * 2 + f;
                const int sw = ki & 7;
                const s8v af0 = *(const s8v*)(sAu + ((0 * 16 + ki) * 64 + (lane ^ sw)) * 8);
                const s8v af1 = *(const s8v*)(sAu + ((1 * 16 + ki) * 64 + (lane ^ sw)) * 8);
                const s8v b0 = f ? bc01 : bc00;
                const s8v b1f = f ? bc11 : bc10;
                a00 = __builtin_amdgcn_mfma_f32_32x32x16_bf16(af0, b0,  a00, 0, 0, 0);
                a01 = __builtin_amdgcn_mfma_f32_32x32x16_bf16(af0, b1f, a01, 0, 0, 0);
                a10 = __builtin_amdgcn_mfma_f32_32x32x16_bf16(af1, b0,  a10, 0, 0, 0);
                a11 = __builtin_amdgcn_mfma_f32_32x32x16_bf16(af1, b1f, a11, 0, 0, 0);
            }
            bc00 = bn00; bc01 = bn01; bc10 = bn10; bc11 = bn11;
        }

        // ---- contraction of this slab from acc registers into LDS res ----
        #pragma unroll
        for (int mt = 0; mt < 2; ++mt) {
            const f16v accA = mt ? a10 : a00;
            const f16v accB = mt ? a11 : a01;
            #pragma unroll
            for (int qq = 0; qq < 4; ++qq) {
                const int ebase = mt * 32 + qq * 8 + eh5 * 4;  // e quad-contig in reg
                if (r < 2) {
                    const float* C = (r == 0) ? sCss : sCvv;
                    const float4 c0 = *(const float4*)(C + i0 * 64 + ebase);
                    const float4 c1 = *(const float4*)(C + i1 * 64 + ebase);
                    #pragma unroll
                    for (int qr = 0; qr < 4; ++qr) {
                        const int q = qq * 4 + qr;
                        const float val = ((const float*)&c0)[qr] * accA[q]
                                        + ((const float*)&c1)[qr] * accB[q];
                        atomicAdd(&resS[(ebase + qr) * 16 + jj], val);
                    }
                } else if (r == 2) {
                    const float4 c0 = *(const float4*)(sCsv + i0 * 64 + ebase);
                    const float4 c1 = *(const float4*)(sCsv + i1 * 64 + ebase);
                    const float4 yx = *(const float4*)(sAttrT + 1 * 64 + ebase);
                    const float4 yy = *(const float4*)(sAttrT + 2 * 64 + ebase);
                    const float4 yz = *(const float4*)(sAttrT + 3 * 64 + ebase);
                    #pragma unroll
                    for (int qr = 0; qr < 4; ++qr) {
                        const int q = qq * 4 + qr;
                        const float p = ((const float*)&c0)[qr] * accA[q]
                                      + ((const float*)&c1)[qr] * accB[q];
                        const int base = (ebase + qr) * 48 + jj * 3;
                        atomicAdd(&resV[base + 0], p * ((const float*)&yx)[qr]);
                        atomicAdd(&resV[base + 1], p * ((const float*)&yy)[qr]);
                        atomicAdd(&resV[base + 2], p * ((const float*)&yz)[qr]);
                    }
                } else {
                    #pragma unroll
                    for (int a = 0; a < 3; ++a) {
                        const float4 c0 = *(const float4*)(sCvs + (i0 * 3 + a) * 64 + ebase);
                        const float4 c1 = *(const float4*)(sCvs + (i1 * 3 + a) * 64 + ebase);
                        #pragma unroll
                        for (int qr = 0; qr < 4; ++qr) {
                            const int q = qq * 4 + qr;
                            const float val = ((const float*)&c0)[qr] * accA[q]
                                            + ((const float*)&c1)[qr] * accB[q];
                            atomicAdd(&resV[(ebase + qr) * 48 + jj * 3 + a], val);
                        }
                    }
                }
            }
        }
    }
    __syncthreads();

    // ---------------- phase 4: scatter to output ----------------
    {
        const int e = t >> 2, qq = t & 3;
        const int ge = e0 + e;
        if (ge < E) {
            float* op = out + (size_t)sDst[e] * 64 + qq * 16;
            const float* rp = (qq == 0) ? (resS + e * 16) : (resV + e * 48 + (qq - 1) * 16);
            #pragma unroll
            for (int c = 0; c < 16; ++c) {
#if defined(__HIP_DEVICE_COMPILE__)
                unsafeAtomicAdd(op + c, rp[c]);
#else
                atomicAdd(op + c, rp[c]);
#endif
            }
        }
    }
}

extern "C" void kernel_launch(void* const* d_in, const int* in_sizes, int n_in,
                              void* d_out, int out_size, void* d_ws, size_t ws_size,
                              hipStream_t stream)
{
    const float* node_features = (const float*)d_in[0];
    const float* edge_attr     = (const float*)d_in[1];
    const float* edge_emb      = (const float*)d_in[2];
    const float* W1            = (const float*)d_in[3];
    const float* b1            = (const float*)d_in[4];
    const float* W2            = (const float*)d_in[5];
    const float* b2            = (const float*)d_in[6];
    const int*   edge_src      = (const int*)d_in[7];
    const int*   edge_dst      = (const int*)d_in[8];
    float*       out           = (float*)d_out;

    const int E = in_sizes[7];
    const int N = out_size / 64;
    const float num_neigh = (float)E / (float)N;
    // c_s = sqrt(1/32); c_v/sqrt3 = c_s; fold final 1/sqrt(num_neigh)
    const float CC = 0.17677669529663689f / sqrtf(num_neigh);

    hipMemsetAsync(out, 0, (size_t)out_size * sizeof(float), stream);

    unsigned short* W2bf = (unsigned short*)d_ws;   // 512 KB bf16 [1024][256]
    conv_w2<<<256, 256, 0, stream>>>(W2, W2bf);

    const int blocks = (E + TE - 1) / TE;
    nequip_mfma<<<blocks, NTHR, 0, stream>>>(
        node_features, edge_attr, edge_emb, W1, b1, W2bf, b2,
        edge_src, edge_dst, out, E, CC);
}

// Round 3
// 1103.259 us; speedup vs baseline: 1.1148x; 1.1103x over previous
//
#include <hip/hip_runtime.h>
#include <math.h>

// ---------------------------------------------------------------------------
// NequIP fused edge kernel, round 2: kill the global fp32 atomic scatter.
//
// R1 post-mortem: 10.24M device-scope fp32 atomicAdds write-through to HBM
// (WRITE_SIZE 320MB for a 2.5MB output) at ~3.5 atomics/cycle device-wide ->
// ~1.2ms floor regardless of compute. Replace with:
//   main kernel  : per-edge features -> F[E][64] in d_ws, plain float4 stores
//   hist/scan/fill: device-built CSR (edge ids bucketed by dst)
//   gather       : one wave per node, lane=feature, sum edge rows, write out
// ---------------------------------------------------------------------------

typedef __attribute__((ext_vector_type(8))) short s8v;    // 8 x bf16 (4 VGPR)
typedef __attribute__((ext_vector_type(16))) float f16v;  // 32x32 acc (16 f32)
typedef unsigned short ushort_t;
typedef unsigned int uint_t;

#define NTHR 256
#define TE 64

__device__ __forceinline__ ushort_t f2bf(float x) {
    uint_t u = __float_as_uint(x);
    u += 0x7fffu + ((u >> 16) & 1u);   // round-to-nearest-even
    return (ushort_t)(u >> 16);
}

// W2 [256][1024] fp32 -> W2bf [1024][256] bf16 (transposed, k-contiguous).
__global__ void conv_w2(const float* __restrict__ W2, ushort_t* __restrict__ W2bf) {
    int idx = blockIdx.x * 256 + threadIdx.x;      // 65536 threads, 4 k each
    int n  = idx & 1023;
    int k4 = (idx >> 10) << 2;
    uint_t lo = (uint_t)f2bf(W2[(size_t)(k4 + 0) * 1024 + n]) |
                ((uint_t)f2bf(W2[(size_t)(k4 + 1) * 1024 + n]) << 16);
    uint_t hi = (uint_t)f2bf(W2[(size_t)(k4 + 2) * 1024 + n]) |
                ((uint_t)f2bf(W2[(size_t)(k4 + 3) * 1024 + n]) << 16);
    ((uint2*)W2bf)[(n * 256 + k4) >> 2] = make_uint2(lo, hi);
}

// ---------------- CSR build ----------------
__global__ void hist_kernel(const int* __restrict__ edst, int* __restrict__ counts, int E) {
    int i = blockIdx.x * 256 + threadIdx.x;
    if (i < E) atomicAdd(&counts[edst[i]], 1);
}

// 1 block, 1024 threads: exclusive scan of counts[N] -> offsets[N+1]
__global__ __launch_bounds__(1024)
void scan_kernel(const int* __restrict__ counts, int* __restrict__ offsets, int N) {
    __shared__ int sdata[1024];
    const int t = threadIdx.x;
    const int C = (N + 1023) / 1024;
    const int lo = t * C;
    const int hi = min(lo + C, N);
    int sum = 0;
    for (int i = lo; i < hi; ++i) sum += counts[i];
    sdata[t] = sum;
    __syncthreads();
    for (int s = 1; s < 1024; s <<= 1) {
        int v = (t >= s) ? sdata[t - s] : 0;
        __syncthreads();
        sdata[t] += v;
        __syncthreads();
    }
    int run = sdata[t] - sum;          // exclusive prefix of this chunk
    for (int i = lo; i < hi; ++i) { offsets[i] = run; run += counts[i]; }
    if (t == 1023) offsets[N] = run;   // == E
}

__global__ void fill_kernel(const int* __restrict__ edst,
                            const int* __restrict__ offsets,
                            int* __restrict__ cursor,
                            int* __restrict__ elist, int E) {
    int i = blockIdx.x * 256 + threadIdx.x;
    if (i < E) {
        int d = edst[i];
        int pos = offsets[d] + atomicAdd(&cursor[d], 1);
        elist[pos] = i;
    }
}

// ---------------- gather: one wave per node ----------------
__global__ __launch_bounds__(256)
void gather_kernel(const float* __restrict__ F,
                   const int* __restrict__ offsets,
                   const int* __restrict__ elist,
                   float* __restrict__ out, int N) {
    const int lane = threadIdx.x & 63;
    const int node = (blockIdx.x * 256 + threadIdx.x) >> 6;
    if (node >= N) return;
    const int base = offsets[node];
    const int end  = offsets[node + 1];
    float acc = 0.f;
    for (int j0 = base; j0 < end; j0 += 64) {
        const int rem = min(64, end - j0);
        int myeid = (lane < rem) ? elist[j0 + lane] : 0;
        int j = 0;
        for (; j + 4 <= rem; j += 4) {
            const int a0 = __shfl(myeid, j    );
            const int a1 = __shfl(myeid, j + 1);
            const int a2 = __shfl(myeid, j + 2);
            const int a3 = __shfl(myeid, j + 3);
            const float r0 = F[(size_t)a0 * 64 + lane];
            const float r1 = F[(size_t)a1 * 64 + lane];
            const float r2 = F[(size_t)a2 * 64 + lane];
            const float r3 = F[(size_t)a3 * 64 + lane];
            acc += (r0 + r1) + (r2 + r3);
        }
        for (; j < rem; ++j) {
            const int a = __shfl(myeid, j);
            acc += F[(size_t)a * 64 + lane];
        }
    }
    out[(size_t)node * 64 + lane] = acc;
}

// ---------------- main fused edge kernel ----------------
__global__ __launch_bounds__(NTHR, 2)
void nequip_mfma(const float* __restrict__ nodef,
                 const float* __restrict__ eattr,
                 const float* __restrict__ eemb,
                 const float* __restrict__ W1,
                 const float* __restrict__ b1,
                 const ushort_t* __restrict__ W2bf,
                 const float* __restrict__ b2,
                 const int* __restrict__ esrc,
                 float* __restrict__ F,
                 int E, float CC)
{
    __shared__ __align__(16) ushort_t sAu[TE * 256];   // 32 KB h bf16, frag order
    __shared__ __align__(16) float sEmb[TE * 18];      // 4.5 KB
    __shared__ __align__(16) float sCss[16 * 64];      // coef[i][e] = CC*y0*s
    __shared__ __align__(16) float sCvv[16 * 64];      // CC/sqrt3*(y1.v)
    __shared__ __align__(16) float sCsv[16 * 64];      // CC*s
    __shared__ __align__(16) float sCvs[48 * 64];      // [(i*3+a)][e] = CC*y0*v
    __shared__ __align__(16) float sAttrT[4 * 64];     // [c][e] y0,y1x,y1y,y1z
    __shared__ __align__(16) float resS[64 * 16];      // out_s accum
    __shared__ __align__(16) float resV[64 * 48];      // out_v accum

    const int t  = threadIdx.x;
    const int e0 = blockIdx.x * TE;

    // ---------------- phase 1: staging + coefs + res zero ----------------
    for (int idx = t; idx < TE * 18; idx += NTHR) {
        size_t g = (size_t)e0 * 18 + idx;
        sEmb[idx] = (g < (size_t)E * 18) ? eemb[g] : 0.f;
    }
    if (t < TE) {
        int ge = e0 + t;
        float4 a = make_float4(0.f, 0.f, 0.f, 0.f);
        if (ge < E) a = *(const float4*)(eattr + (size_t)ge * 4);
        sAttrT[0 * 64 + t] = a.x; sAttrT[1 * 64 + t] = a.y;
        sAttrT[2 * 64 + t] = a.z; sAttrT[3 * 64 + t] = a.w;
    }
    for (int idx = t; idx < 64 * 16; idx += NTHR) resS[idx] = 0.f;
    for (int idx = t; idx < 64 * 48; idx += NTHR) resV[idx] = 0.f;

    {   // coef tables: thread t -> edge e = t>>2, i-quad iq = t&3
        const int e = t >> 2, iq = t & 3;
        const int ge = e0 + e;
        const bool ok = ge < E;
        float y0 = 0.f, y1x = 0.f, y1y = 0.f, y1z = 0.f;
        int src = 0;
        if (ok) {
            float4 a = *(const float4*)(eattr + (size_t)ge * 4);
            y0 = a.x; y1x = a.y; y1y = a.z; y1z = a.w;
            src = esrc[ge];
        }
        const float* xp = nodef + (size_t)src * 64;
        float4 z = make_float4(0.f, 0.f, 0.f, 0.f);
        float4 sv = ok ? *(const float4*)(xp + iq * 4) : z;
        float4 v0 = ok ? *(const float4*)(xp + 16 + iq * 12) : z;
        float4 v1 = ok ? *(const float4*)(xp + 16 + iq * 12 + 4) : z;
        float4 v2 = ok ? *(const float4*)(xp + 16 + iq * 12 + 8) : z;
        const float K3 = CC * 0.57735026918962576f;   // CC/sqrt(3)
        float sarr[4] = { sv.x, sv.y, sv.z, sv.w };
        float varr[12] = { v0.x, v0.y, v0.z, v0.w, v1.x, v1.y, v1.z, v1.w,
                           v2.x, v2.y, v2.z, v2.w };
        #pragma unroll
        for (int j = 0; j < 4; ++j) {
            const int i = iq * 4 + j;
            const float s  = sarr[j];
            const float vx = varr[j * 3 + 0], vy = varr[j * 3 + 1], vz = varr[j * 3 + 2];
            sCss[i * 64 + e] = CC * y0 * s;
            sCvv[i * 64 + e] = K3 * (y1x * vx + y1y * vy + y1z * vz);
            sCsv[i * 64 + e] = CC * s;
            sCvs[(i * 3 + 0) * 64 + e] = CC * y0 * vx;
            sCvs[(i * 3 + 1) * 64 + e] = CC * y0 * vy;
            sCvs[(i * 3 + 2) * 64 + e] = CC * y0 * vz;
        }
    }
    __syncthreads();

    // ---------------- B-frag addressing + initial prefetch ----------------
    const int lane = t & 63;
    const int w    = t >> 6;          // wave id 0..3
    const int l31  = lane & 31;
    const int eh5  = lane >> 5;
    const ushort_t* Bbase0 = W2bf + ((size_t)(w * 32 + l31) * 256 + eh5 * 8);
    const ushort_t* Bbase1 = W2bf + ((size_t)((w + 4) * 32 + l31) * 256 + eh5 * 8);

    s8v bc00 = *(const s8v*)(Bbase0);
    s8v bc01 = *(const s8v*)(Bbase0 + 16);
    s8v bc10 = *(const s8v*)(Bbase1);
    s8v bc11 = *(const s8v*)(Bbase1 + 16);

    // ---------------- phase 2: h = silu(emb@W1+b1) -> sA (bf16 frag order) --
    {
        const int p = t & 127;         // column pair p -> cols 2p, 2p+1
        const int ehalf = t >> 7;      // edge half (e = ehalf*32 + er)
        const int n0 = 2 * p;
        float w1a[18], w1b[18];
        #pragma unroll
        for (int m = 0; m < 18; ++m) {
            float2 wv = *(const float2*)(W1 + m * 256 + n0);
            w1a[m] = wv.x; w1b[m] = wv.y;
        }
        const float2 bv = *(const float2*)(b1 + n0);
        const int ki = p >> 3;                      // k-iter of this col pair
        const int wordBase = (ehalf * 16 + ki) * 64;
        const int wsub = p & 3;                     // word within 16B frag
        uint_t* sA32 = (uint_t*)sAu;
        for (int er = 0; er < 32; ++er) {
            const int e = ehalf * 32 + er;
            float a0 = bv.x, a1 = bv.y;
            const float* ep = sEmb + e * 18;
            #pragma unroll
            for (int m = 0; m < 18; ++m) {
                const float em = ep[m];
                a0 = fmaf(em, w1a[m], a0);
                a1 = fmaf(em, w1b[m], a1);
            }
            a0 = a0 / (1.f + __expf(-a0));          // silu
            a1 = a1 / (1.f + __expf(-a1));
            const uint_t pk = (uint_t)f2bf(a0) | ((uint_t)f2bf(a1) << 16);
            const int lane_s  = (e & 31) + 32 * ((p >> 2) & 1);
            const int lane_sw = lane_s ^ (ki & 7);  // XOR swizzle (bank spread)
            sA32[(wordBase + lane_sw) * 4 + wsub] = pk;
        }
    }
    __syncthreads();

    // ---------------- phase 3: MFMA K-loop + per-slab contraction ----------
    const int ip = (lane >> 4) & 1;   // i parity within an N-tile
    const int jj = lane & 15;         // output column j
    const int i0 = 2 * w + ip;        // i of tile nt=w
    const int i1 = 2 * w + 8 + ip;    // i of tile nt=w+4

    #pragma unroll 1
    for (int r = 0; r < 4; ++r) {     // slab = weight type (ss, vv, sv, vs)
        const float bz0 = b2[r * 256 + w * 32 + l31];
        const float bz1 = b2[r * 256 + (w + 4) * 32 + l31];
        f16v a00, a01, a10, a11;      // [mtile][ntile]
        #pragma unroll
        for (int q = 0; q < 16; ++q) { a00[q] = bz0; a01[q] = bz1; a10[q] = bz0; a11[q] = bz1; }

        #pragma unroll
        for (int kk = 0; kk < 8; ++kk) {          // kiter pairs
            const int s2 = r * 8 + kk;
            const int s3 = (s2 + 1 < 32) ? (s2 + 1) : s2;   // clamp, harmless reload
            const int rn = s3 >> 3, kn = s3 & 7;
            const ushort_t* p0 = Bbase0 + (size_t)rn * 65536 + kn * 32;
            const ushort_t* p1 = Bbase1 + (size_t)rn * 65536 + kn * 32;
            s8v bn00 = *(const s8v*)(p0);
            s8v bn01 = *(const s8v*)(p0 + 16);
            s8v bn10 = *(const s8v*)(p1);
            s8v bn11 = *(const s8v*)(p1 + 16);

            #pragma unroll
            for (int f = 0; f < 2; ++f) {
                const int ki = kk * 2 + f;
                const int sw = ki & 7;
                const s8v af0 = *(const s8v*)(sAu + ((0 * 16 + ki) * 64 + (lane ^ sw)) * 8);
                const s8v af1 = *(const s8v*)(sAu + ((1 * 16 + ki) * 64 + (lane ^ sw)) * 8);
                const s8v b0 = f ? bc01 : bc00;
                const s8v b1f = f ? bc11 : bc10;
                a00 = __builtin_amdgcn_mfma_f32_32x32x16_bf16(af0, b0,  a00, 0, 0, 0);
                a01 = __builtin_amdgcn_mfma_f32_32x32x16_bf16(af0, b1f, a01, 0, 0, 0);
                a10 = __builtin_amdgcn_mfma_f32_32x32x16_bf16(af1, b0,  a10, 0, 0, 0);
                a11 = __builtin_amdgcn_mfma_f32_32x32x16_bf16(af1, b1f, a11, 0, 0, 0);
            }
            bc00 = bn00; bc01 = bn01; bc10 = bn10; bc11 = bn11;
        }

        // ---- contraction of this slab from acc registers into LDS res ----
        #pragma unroll
        for (int mt = 0; mt < 2; ++mt) {
            const f16v accA = mt ? a10 : a00;
            const f16v accB = mt ? a11 : a01;
            #pragma unroll
            for (int qq = 0; qq < 4; ++qq) {
                const int ebase = mt * 32 + qq * 8 + eh5 * 4;  // e quad-contig in reg
                if (r < 2) {
                    const float* C = (r == 0) ? sCss : sCvv;
                    const float4 c0 = *(const float4*)(C + i0 * 64 + ebase);
                    const float4 c1 = *(const float4*)(C + i1 * 64 + ebase);
                    #pragma unroll
                    for (int qr = 0; qr < 4; ++qr) {
                        const int q = qq * 4 + qr;
                        const float val = ((const float*)&c0)[qr] * accA[q]
                                        + ((const float*)&c1)[qr] * accB[q];
                        atomicAdd(&resS[(ebase + qr) * 16 + jj], val);
                    }
                } else if (r == 2) {
                    const float4 c0 = *(const float4*)(sCsv + i0 * 64 + ebase);
                    const float4 c1 = *(const float4*)(sCsv + i1 * 64 + ebase);
                    const float4 yx = *(const float4*)(sAttrT + 1 * 64 + ebase);
                    const float4 yy = *(const float4*)(sAttrT + 2 * 64 + ebase);
                    const float4 yz = *(const float4*)(sAttrT + 3 * 64 + ebase);
                    #pragma unroll
                    for (int qr = 0; qr < 4; ++qr) {
                        const int q = qq * 4 + qr;
                        const float p = ((const float*)&c0)[qr] * accA[q]
                                      + ((const float*)&c1)[qr] * accB[q];
                        const int base = (ebase + qr) * 48 + jj * 3;
                        atomicAdd(&resV[base + 0], p * ((const float*)&yx)[qr]);
                        atomicAdd(&resV[base + 1], p * ((const float*)&yy)[qr]);
                        atomicAdd(&resV[base + 2], p * ((const float*)&yz)[qr]);
                    }
                } else {
                    #pragma unroll
                    for (int a = 0; a < 3; ++a) {
                        const float4 c0 = *(const float4*)(sCvs + (i0 * 3 + a) * 64 + ebase);
                        const float4 c1 = *(const float4*)(sCvs + (i1 * 3 + a) * 64 + ebase);
                        #pragma unroll
                        for (int qr = 0; qr < 4; ++qr) {
                            const int q = qq * 4 + qr;
                            const float val = ((const float*)&c0)[qr] * accA[q]
                                            + ((const float*)&c1)[qr] * accB[q];
                            atomicAdd(&resV[(ebase + qr) * 48 + jj * 3 + a], val);
                        }
                    }
                }
            }
        }
    }
    __syncthreads();

    // ---------------- phase 4: plain coalesced store to F[e][64] ----------
    {
        const int e = t >> 2, qq = t & 3;
        const int ge = e0 + e;
        if (ge < E) {
            float* fp = F + (size_t)ge * 64 + qq * 16;
            const float* rp = (qq == 0) ? (resS + e * 16) : (resV + e * 48 + (qq - 1) * 16);
            #pragma unroll
            for (int c = 0; c < 16; c += 4)
                *(float4*)(fp + c) = *(const float4*)(rp + c);
        }
    }
}

extern "C" void kernel_launch(void* const* d_in, const int* in_sizes, int n_in,
                              void* d_out, int out_size, void* d_ws, size_t ws_size,
                              hipStream_t stream)
{
    const float* node_features = (const float*)d_in[0];
    const float* edge_attr     = (const float*)d_in[1];
    const float* edge_emb      = (const float*)d_in[2];
    const float* W1            = (const float*)d_in[3];
    const float* b1            = (const float*)d_in[4];
    const float* W2            = (const float*)d_in[5];
    const float* b2            = (const float*)d_in[6];
    const int*   edge_src      = (const int*)d_in[7];
    const int*   edge_dst      = (const int*)d_in[8];
    float*       out           = (float*)d_out;

    const int E = in_sizes[7];
    const int N = out_size / 64;
    const float num_neigh = (float)E / (float)N;
    const float CC = 0.17677669529663689f / sqrtf(num_neigh);

    // ---- workspace layout ----
    char* ws = (char*)d_ws;
    size_t off = 0;
    auto alloc = [&](size_t bytes) { char* p = ws + off; off = (off + bytes + 255) & ~(size_t)255; return p; };
    ushort_t* W2bf   = (ushort_t*)alloc((size_t)1024 * 256 * 2);
    int*      counts = (int*)alloc((size_t)N * 4);
    int*      offs   = (int*)alloc((size_t)(N + 1) * 4);
    int*      cursor = (int*)alloc((size_t)N * 4);
    int*      elist  = (int*)alloc((size_t)E * 4);
    float*    F      = (float*)alloc((size_t)E * 64 * 4);
    (void)ws_size;

    hipMemsetAsync(counts, 0, (size_t)N * 4, stream);
    hipMemsetAsync(cursor, 0, (size_t)N * 4, stream);

    conv_w2<<<256, 256, 0, stream>>>(W2, W2bf);
    hist_kernel<<<(E + 255) / 256, 256, 0, stream>>>(edge_dst, counts, E);
    scan_kernel<<<1, 1024, 0, stream>>>(counts, offs, N);
    fill_kernel<<<(E + 255) / 256, 256, 0, stream>>>(edge_dst, offs, cursor, elist, E);

    const int blocks = (E + TE - 1) / TE;
    nequip_mfma<<<blocks, NTHR, 0, stream>>>(
        node_features, edge_attr, edge_emb, W1, b1, W2bf, b2,
        edge_src, F, E, CC);

    gather_kernel<<<(N + 3) / 4, 256, 0, stream>>>(F, offs, elist, out, N);
}

// Round 4
// 469.535 us; speedup vs baseline: 2.6193x; 2.3497x over previous
//
#include <hip/hip_runtime.h>
#include <math.h>

// ---------------------------------------------------------------------------
// NequIP fused, round 3: eliminate ALL LDS atomics (R2's real stall).
//
// R2 post-mortem: 256 fp32 LDS atomicAdds/thread lower to ds CAS loops
// (no -munsafe-fp-atomics) with 8-way same-address contention -> ~950us of
// dead-pipe stall (MfmaUtil 3.3%, VALUBusy 5.3%).
//
// Redesign: mfma 16x16x32; wave = (e-half mhalf, slab-pair rpair).
//   - wave owns 2 m-tiles (32 edges) and loops 32 n-tiles (2 slabs x 16 i),
//     n = r*256 + i*16 + j  (natural W2 order: j contiguous).
//   - sum over i = serial per-wave register accumulation; no cross-lane ops.
//   - rpair 0 waves fully own out_s, rpair 1 waves fully own out_v
//     -> resS/resV written once by a single owner, plain ds_write.
//   - A (h bf16) preloaded to 64 VGPRs from XOR-swizzled LDS; B register-
//     prefetched 1 tile (8 frags) ahead from L2-resident W2bf.
// ---------------------------------------------------------------------------

typedef __attribute__((ext_vector_type(8))) short s8v;    // 8 x bf16 (4 VGPR)
typedef __attribute__((ext_vector_type(4))) float f4v;    // 16x16 acc (4 f32)
typedef unsigned short ushort_t;
typedef unsigned int uint_t;

#define NTHR 256
#define TE 64

__device__ __forceinline__ ushort_t f2bf(float x) {
    uint_t u = __float_as_uint(x);
    u += 0x7fffu + ((u >> 16) & 1u);   // round-to-nearest-even
    return (ushort_t)(u >> 16);
}

// W2 [256][1024] fp32 -> W2bf [1024][256] bf16 (transposed, k-contiguous).
__global__ void conv_w2(const float* __restrict__ W2, ushort_t* __restrict__ W2bf) {
    int idx = blockIdx.x * 256 + threadIdx.x;      // 65536 threads, 4 k each
    int n  = idx & 1023;
    int k4 = (idx >> 10) << 2;
    uint_t lo = (uint_t)f2bf(W2[(size_t)(k4 + 0) * 1024 + n]) |
                ((uint_t)f2bf(W2[(size_t)(k4 + 1) * 1024 + n]) << 16);
    uint_t hi = (uint_t)f2bf(W2[(size_t)(k4 + 2) * 1024 + n]) |
                ((uint_t)f2bf(W2[(size_t)(k4 + 3) * 1024 + n]) << 16);
    ((uint2*)W2bf)[(n * 256 + k4) >> 2] = make_uint2(lo, hi);
}

// ---------------- CSR build ----------------
__global__ void hist_kernel(const int* __restrict__ edst, int* __restrict__ counts, int E) {
    int i = blockIdx.x * 256 + threadIdx.x;
    if (i < E) atomicAdd(&counts[edst[i]], 1);
}

__global__ __launch_bounds__(1024)
void scan_kernel(const int* __restrict__ counts, int* __restrict__ offsets, int N) {
    __shared__ int sdata[1024];
    const int t = threadIdx.x;
    const int C = (N + 1023) / 1024;
    const int lo = t * C;
    const int hi = min(lo + C, N);
    int sum = 0;
    for (int i = lo; i < hi; ++i) sum += counts[i];
    sdata[t] = sum;
    __syncthreads();
    for (int s = 1; s < 1024; s <<= 1) {
        int v = (t >= s) ? sdata[t - s] : 0;
        __syncthreads();
        sdata[t] += v;
        __syncthreads();
    }
    int run = sdata[t] - sum;
    for (int i = lo; i < hi; ++i) { offsets[i] = run; run += counts[i]; }
    if (t == 1023) offsets[N] = run;
}

__global__ void fill_kernel(const int* __restrict__ edst,
                            const int* __restrict__ offsets,
                            int* __restrict__ cursor,
                            int* __restrict__ elist, int E) {
    int i = blockIdx.x * 256 + threadIdx.x;
    if (i < E) {
        int d = edst[i];
        int pos = offsets[d] + atomicAdd(&cursor[d], 1);
        elist[pos] = i;
    }
}

// ---------------- gather: one wave per node ----------------
__global__ __launch_bounds__(256)
void gather_kernel(const float* __restrict__ F,
                   const int* __restrict__ offsets,
                   const int* __restrict__ elist,
                   float* __restrict__ out, int N) {
    const int lane = threadIdx.x & 63;
    const int node = (blockIdx.x * 256 + threadIdx.x) >> 6;
    if (node >= N) return;
    const int base = offsets[node];
    const int end  = offsets[node + 1];
    float acc = 0.f;
    for (int j0 = base; j0 < end; j0 += 64) {
        const int rem = min(64, end - j0);
        int myeid = (lane < rem) ? elist[j0 + lane] : 0;
        int j = 0;
        for (; j + 4 <= rem; j += 4) {
            const int a0 = __shfl(myeid, j    );
            const int a1 = __shfl(myeid, j + 1);
            const int a2 = __shfl(myeid, j + 2);
            const int a3 = __shfl(myeid, j + 3);
            const float r0 = F[(size_t)a0 * 64 + lane];
            const float r1 = F[(size_t)a1 * 64 + lane];
            const float r2 = F[(size_t)a2 * 64 + lane];
            const float r3 = F[(size_t)a3 * 64 + lane];
            acc += (r0 + r1) + (r2 + r3);
        }
        for (; j < rem; ++j) {
            const int a = __shfl(myeid, j);
            acc += F[(size_t)a * 64 + lane];
        }
    }
    out[(size_t)node * 64 + lane] = acc;
}

// ---------------- main fused edge kernel ----------------
__global__ __launch_bounds__(NTHR, 2)
void nequip_mfma(const float* __restrict__ nodef,
                 const float* __restrict__ eattr,
                 const float* __restrict__ eemb,
                 const float* __restrict__ W1,
                 const float* __restrict__ b1,
                 const ushort_t* __restrict__ W2bf,
                 const float* __restrict__ b2,
                 const int* __restrict__ esrc,
                 float* __restrict__ F,
                 int E, float CC)
{
    __shared__ __align__(16) ushort_t sAu[TE * 256];   // 32 KB h bf16, A-frag order
    __shared__ __align__(16) float sEmb[TE * 18];      // 4.5 KB
    __shared__ __align__(16) float sCss[16 * 64];      // coef[i][e] = CC*y0*s
    __shared__ __align__(16) float sCvv[16 * 64];      // CC/sqrt3*(y1.v)
    __shared__ __align__(16) float sCsv[16 * 64];      // CC*s
    __shared__ __align__(16) float sCvs[48 * 64];      // [(i*3+a)][e] = CC*y0*v
    __shared__ __align__(16) float sAttrT[4 * 64];     // [c][e]
    __shared__ __align__(16) float resS[64 * 16];      // single-owner, no init
    __shared__ __align__(16) float resV[64 * 48];      // single-owner, no init

    const int t  = threadIdx.x;
    const int e0 = blockIdx.x * TE;

    // ---------------- phase 1: staging + coef tables ----------------
    for (int idx = t; idx < TE * 18; idx += NTHR) {
        size_t g = (size_t)e0 * 18 + idx;
        sEmb[idx] = (g < (size_t)E * 18) ? eemb[g] : 0.f;
    }
    if (t < TE) {
        int ge = e0 + t;
        float4 a = make_float4(0.f, 0.f, 0.f, 0.f);
        if (ge < E) a = *(const float4*)(eattr + (size_t)ge * 4);
        sAttrT[0 * 64 + t] = a.x; sAttrT[1 * 64 + t] = a.y;
        sAttrT[2 * 64 + t] = a.z; sAttrT[3 * 64 + t] = a.w;
    }
    {   // thread t -> edge e = t>>2, i-quad iq = t&3
        const int e = t >> 2, iq = t & 3;
        const int ge = e0 + e;
        const bool ok = ge < E;
        float y0 = 0.f, y1x = 0.f, y1y = 0.f, y1z = 0.f;
        int src = 0;
        if (ok) {
            float4 a = *(const float4*)(eattr + (size_t)ge * 4);
            y0 = a.x; y1x = a.y; y1y = a.z; y1z = a.w;
            src = esrc[ge];
        }
        const float* xp = nodef + (size_t)src * 64;
        float4 z = make_float4(0.f, 0.f, 0.f, 0.f);
        float4 sv = ok ? *(const float4*)(xp + iq * 4) : z;
        float4 v0 = ok ? *(const float4*)(xp + 16 + iq * 12) : z;
        float4 v1 = ok ? *(const float4*)(xp + 16 + iq * 12 + 4) : z;
        float4 v2 = ok ? *(const float4*)(xp + 16 + iq * 12 + 8) : z;
        const float K3 = CC * 0.57735026918962576f;   // CC/sqrt(3)
        float sarr[4] = { sv.x, sv.y, sv.z, sv.w };
        float varr[12] = { v0.x, v0.y, v0.z, v0.w, v1.x, v1.y, v1.z, v1.w,
                           v2.x, v2.y, v2.z, v2.w };
        #pragma unroll
        for (int j = 0; j < 4; ++j) {
            const int i = iq * 4 + j;
            const float s  = sarr[j];
            const float vx = varr[j * 3 + 0], vy = varr[j * 3 + 1], vz = varr[j * 3 + 2];
            sCss[i * 64 + e] = CC * y0 * s;
            sCvv[i * 64 + e] = K3 * (y1x * vx + y1y * vy + y1z * vz);
            sCsv[i * 64 + e] = CC * s;
            sCvs[(i * 3 + 0) * 64 + e] = CC * y0 * vx;
            sCvs[(i * 3 + 1) * 64 + e] = CC * y0 * vy;
            sCvs[(i * 3 + 2) * 64 + e] = CC * y0 * vz;
        }
    }
    __syncthreads();

    // ---- phase 2: h = silu(emb@W1+b1) -> sAu, 16x16x32 A-frag order ----
    // element (e,k): kk=k>>5, lane=(e&15)+16*((k>>3)&3), slot=k&7; lane^kk swizzle
    {
        const int p = t & 127;         // column pair p -> cols 2p, 2p+1
        const int ehalf = t >> 7;
        const int n0 = 2 * p;
        float w1a[18], w1b[18];
        #pragma unroll
        for (int m = 0; m < 18; ++m) {
            float2 wv = *(const float2*)(W1 + m * 256 + n0);
            w1a[m] = wv.x; w1b[m] = wv.y;
        }
        const float2 bv = *(const float2*)(b1 + n0);
        const int kk = p >> 4;                       // k-iter (0..7)
        const int lhi = 16 * ((p >> 2) & 3);
        const int wsub = p & 3;                      // uint slot within 16B frag
        uint_t* sA32 = (uint_t*)sAu;
        for (int er = 0; er < 32; ++er) {
            const int e = ehalf * 32 + er;
            float a0 = bv.x, a1 = bv.y;
            const float* ep = sEmb + e * 18;
            #pragma unroll
            for (int m = 0; m < 18; ++m) {
                const float em = ep[m];
                a0 = fmaf(em, w1a[m], a0);
                a1 = fmaf(em, w1b[m], a1);
            }
            a0 = a0 / (1.f + __expf(-a0));          // silu
            a1 = a1 / (1.f + __expf(-a1));
            const uint_t pk = (uint_t)f2bf(a0) | ((uint_t)f2bf(a1) << 16);
            const int lane_sw = ((e & 15) + lhi) ^ kk;
            sA32[(((e >> 4) * 8 + kk) * 64 + lane_sw) * 4 + wsub] = pk;
        }
    }
    __syncthreads();

    // ---------------- phase 3: per-wave n-tile loop ----------------
    const int lane  = t & 63;
    const int w     = t >> 6;
    const int mhalf = w & 1;          // e-half: e in [mhalf*32, +32)
    const int rpair = w >> 1;         // slabs {2rpair, 2rpair+1}
    const int jj    = lane & 15;      // output col j
    const int q4    = lane >> 4;
    const int eb0   = mhalf * 32 + q4 * 4;   // e-base of acc regs, m-tile 0
    const int eb1   = eb0 + 16;              //                     m-tile 1
    const int r0    = rpair * 2;

    // A preload: 2 m-tiles x 8 kk  (64 VGPRs)
    s8v aR0[8], aR1[8];
    #pragma unroll
    for (int kk = 0; kk < 8; ++kk) {
        aR0[kk] = *(const s8v*)(sAu + (((mhalf * 2 + 0) * 8 + kk) * 64 + (lane ^ kk)) * 8);
        aR1[kk] = *(const s8v*)(sAu + (((mhalf * 2 + 1) * 8 + kk) * 64 + (lane ^ kk)) * 8);
    }
    const ushort_t* Bl = W2bf + (size_t)jj * 256 + q4 * 8;  // + nb*256 + kk*32

    if (rpair == 0) {
        float pS0[4] = {0.f, 0.f, 0.f, 0.f}, pS1[4] = {0.f, 0.f, 0.f, 0.f};
        s8v bc[8];
        {
            const int nb = r0 * 256;
            #pragma unroll
            for (int kk = 0; kk < 8; ++kk) bc[kk] = *(const s8v*)(Bl + (size_t)nb * 256 + kk * 32);
        }
        float bz = b2[r0 * 256 + jj];
        #pragma unroll 1
        for (int ti = 0; ti < 32; ++ti) {
            const int tiN = (ti < 31) ? ti + 1 : 31;
            const int nbN = (r0 + (tiN >> 4)) * 256 + (tiN & 15) * 16;
            const float bzN = b2[nbN + jj];
            f4v acc0; acc0[0] = bz; acc0[1] = bz; acc0[2] = bz; acc0[3] = bz;
            f4v acc1 = acc0;
            s8v bn[8];
            #pragma unroll
            for (int kk = 0; kk < 8; ++kk) {
                bn[kk] = *(const s8v*)(Bl + (size_t)nbN * 256 + kk * 32);
                acc0 = __builtin_amdgcn_mfma_f32_16x16x32_bf16(aR0[kk], bc[kk], acc0, 0, 0, 0);
                acc1 = __builtin_amdgcn_mfma_f32_16x16x32_bf16(aR1[kk], bc[kk], acc1, 0, 0, 0);
            }
            const int i = ti & 15;
            const float* C = (ti < 16) ? sCss : sCvv;
            const float4 c0 = *(const float4*)(C + i * 64 + eb0);
            const float4 c1 = *(const float4*)(C + i * 64 + eb1);
            pS0[0] = fmaf(c0.x, acc0[0], pS0[0]); pS0[1] = fmaf(c0.y, acc0[1], pS0[1]);
            pS0[2] = fmaf(c0.z, acc0[2], pS0[2]); pS0[3] = fmaf(c0.w, acc0[3], pS0[3]);
            pS1[0] = fmaf(c1.x, acc1[0], pS1[0]); pS1[1] = fmaf(c1.y, acc1[1], pS1[1]);
            pS1[2] = fmaf(c1.z, acc1[2], pS1[2]); pS1[3] = fmaf(c1.w, acc1[3], pS1[3]);
            #pragma unroll
            for (int kk = 0; kk < 8; ++kk) bc[kk] = bn[kk];
            bz = bzN;
        }
        #pragma unroll
        for (int q = 0; q < 4; ++q) {
            resS[(eb0 + q) * 16 + jj] = pS0[q];
            resS[(eb1 + q) * 16 + jj] = pS1[q];
        }
    } else {
        float pSV0[4] = {0.f, 0.f, 0.f, 0.f}, pSV1[4] = {0.f, 0.f, 0.f, 0.f};
        float pVS0[3][4] = {{0.f}}, pVS1[3][4] = {{0.f}};
        s8v bc[8];
        {
            const int nb = r0 * 256;
            #pragma unroll
            for (int kk = 0; kk < 8; ++kk) bc[kk] = *(const s8v*)(Bl + (size_t)nb * 256 + kk * 32);
        }
        float bz = b2[r0 * 256 + jj];
        #pragma unroll 1
        for (int ti = 0; ti < 32; ++ti) {
            const int tiN = (ti < 31) ? ti + 1 : 31;
            const int nbN = (r0 + (tiN >> 4)) * 256 + (tiN & 15) * 16;
            const float bzN = b2[nbN + jj];
            f4v acc0; acc0[0] = bz; acc0[1] = bz; acc0[2] = bz; acc0[3] = bz;
            f4v acc1 = acc0;
            s8v bn[8];
            #pragma unroll
            for (int kk = 0; kk < 8; ++kk) {
                bn[kk] = *(const s8v*)(Bl + (size_t)nbN * 256 + kk * 32);
                acc0 = __builtin_amdgcn_mfma_f32_16x16x32_bf16(aR0[kk], bc[kk], acc0, 0, 0, 0);
                acc1 = __builtin_amdgcn_mfma_f32_16x16x32_bf16(aR1[kk], bc[kk], acc1, 0, 0, 0);
            }
            const int i = ti & 15;
            if (ti < 16) {   // slab sv
                const float4 c0 = *(const float4*)(sCsv + i * 64 + eb0);
                const float4 c1 = *(const float4*)(sCsv + i * 64 + eb1);
                pSV0[0] = fmaf(c0.x, acc0[0], pSV0[0]); pSV0[1] = fmaf(c0.y, acc0[1], pSV0[1]);
                pSV0[2] = fmaf(c0.z, acc0[2], pSV0[2]); pSV0[3] = fmaf(c0.w, acc0[3], pSV0[3]);
                pSV1[0] = fmaf(c1.x, acc1[0], pSV1[0]); pSV1[1] = fmaf(c1.y, acc1[1], pSV1[1]);
                pSV1[2] = fmaf(c1.z, acc1[2], pSV1[2]); pSV1[3] = fmaf(c1.w, acc1[3], pSV1[3]);
            } else {          // slab vs
                #pragma unroll
                for (int a = 0; a < 3; ++a) {
                    const float4 c0 = *(const float4*)(sCvs + (i * 3 + a) * 64 + eb0);
                    const float4 c1 = *(const float4*)(sCvs + (i * 3 + a) * 64 + eb1);
                    pVS0[a][0] = fmaf(c0.x, acc0[0], pVS0[a][0]);
                    pVS0[a][1] = fmaf(c0.y, acc0[1], pVS0[a][1]);
                    pVS0[a][2] = fmaf(c0.z, acc0[2], pVS0[a][2]);
                    pVS0[a][3] = fmaf(c0.w, acc0[3], pVS0[a][3]);
                    pVS1[a][0] = fmaf(c1.x, acc1[0], pVS1[a][0]);
                    pVS1[a][1] = fmaf(c1.y, acc1[1], pVS1[a][1]);
                    pVS1[a][2] = fmaf(c1.z, acc1[2], pVS1[a][2]);
                    pVS1[a][3] = fmaf(c1.w, acc1[3], pVS1[a][3]);
                }
            }
            #pragma unroll
            for (int kk = 0; kk < 8; ++kk) bc[kk] = bn[kk];
            bz = bzN;
        }
        // out_v[e][j][a] = y1[a][e]*pSV + pVS[a]   (scales folded in coefs)
        #pragma unroll
        for (int a = 0; a < 3; ++a) {
            const float4 y0q = *(const float4*)(sAttrT + (1 + a) * 64 + eb0);
            const float4 y1q = *(const float4*)(sAttrT + (1 + a) * 64 + eb1);
            #pragma unroll
            for (int q = 0; q < 4; ++q) {
                resV[(eb0 + q) * 48 + jj * 3 + a] =
                    fmaf(((const float*)&y0q)[q], pSV0[q], pVS0[a][q]);
                resV[(eb1 + q) * 48 + jj * 3 + a] =
                    fmaf(((const float*)&y1q)[q], pSV1[q], pVS1[a][q]);
            }
        }
    }
    __syncthreads();

    // ---------------- phase 4: coalesced store to F[e][64] ----------------
    {
        const int e = t >> 2, qq = t & 3;
        const int ge = e0 + e;
        if (ge < E) {
            float* fp = F + (size_t)ge * 64 + qq * 16;
            const float* rp = (qq == 0) ? (resS + e * 16) : (resV + e * 48 + (qq - 1) * 16);
            #pragma unroll
            for (int c = 0; c < 16; c += 4)
                *(float4*)(fp + c) = *(const float4*)(rp + c);
        }
    }
}

extern "C" void kernel_launch(void* const* d_in, const int* in_sizes, int n_in,
                              void* d_out, int out_size, void* d_ws, size_t ws_size,
                              hipStream_t stream)
{
    const float* node_features = (const float*)d_in[0];
    const float* edge_attr     = (const float*)d_in[1];
    const float* edge_emb      = (const float*)d_in[2];
    const float* W1            = (const float*)d_in[3];
    const float* b1            = (const float*)d_in[4];
    const float* W2            = (const float*)d_in[5];
    const float* b2            = (const float*)d_in[6];
    const int*   edge_src      = (const int*)d_in[7];
    const int*   edge_dst      = (const int*)d_in[8];
    float*       out           = (float*)d_out;

    const int E = in_sizes[7];
    const int N = out_size / 64;
    const float num_neigh = (float)E / (float)N;
    const float CC = 0.17677669529663689f / sqrtf(num_neigh);

    // ---- workspace layout ----
    char* ws = (char*)d_ws;
    size_t off = 0;
    auto alloc = [&](size_t bytes) { char* p = ws + off; off = (off + bytes + 255) & ~(size_t)255; return p; };
    ushort_t* W2bf   = (ushort_t*)alloc((size_t)1024 * 256 * 2);
    int*      counts = (int*)alloc((size_t)N * 4);
    int*      offs   = (int*)alloc((size_t)(N + 1) * 4);
    int*      cursor = (int*)alloc((size_t)N * 4);
    int*      elist  = (int*)alloc((size_t)E * 4);
    float*    F      = (float*)alloc((size_t)E * 64 * 4);
    (void)ws_size;

    hipMemsetAsync(counts, 0, (size_t)N * 4, stream);
    hipMemsetAsync(cursor, 0, (size_t)N * 4, stream);

    conv_w2<<<256, 256, 0, stream>>>(W2, W2bf);
    hist_kernel<<<(E + 255) / 256, 256, 0, stream>>>(edge_dst, counts, E);
    scan_kernel<<<1, 1024, 0, stream>>>(counts, offs, N);
    fill_kernel<<<(E + 255) / 256, 256, 0, stream>>>(edge_dst, offs, cursor, elist, E);

    const int blocks = (E + TE - 1) / TE;
    nequip_mfma<<<blocks, NTHR, 0, stream>>>(
        node_features, edge_attr, edge_emb, W1, b1, W2bf, b2,
        edge_src, F, E, CC);

    gather_kernel<<<(N + 3) / 4, 256, 0, stream>>>(F, offs, elist, out, N);
}